// Round 1
// baseline (378.795 us; speedup 1.0000x reference)
//
#include <hip/hip_runtime.h>
#include <hip/hip_bf16.h>

#define NN 50000
#define NE 600000
#define DD 128

typedef unsigned short u16;
typedef __attribute__((ext_vector_type(8))) short bf16x8;
typedef __attribute__((ext_vector_type(16))) float f32x16;
typedef __attribute__((ext_vector_type(4))) int int4v;

// ---------- LDS layout (dynamic, 128KB + 512B) ----------
#define SM_W1   0        // 64KB: W1t [128 n][256 k] bf16, 16B-chunk XOR swizzle
#define SM_W2   65536    // 32KB: W2t [128 n][128 k] bf16, swizzled
#define SM_PR   98304    // 32KB: pair half-tile / hidden [128 row][128 k] bf16, swizzled
#define SM_DST  131072   // 512B: dst indices
#define SMEM_TOTAL 131584

__device__ __forceinline__ u16 f2b(float x) {
    __hip_bfloat16 b = __float2bfloat16(x);
    union { __hip_bfloat16 b; u16 u; } c; c.b = b; return c.u;
}

__device__ __forceinline__ int4v zero4() {
    int4v v; v[0]=0; v[1]=0; v[2]=0; v[3]=0; return v;
}
__device__ __forceinline__ f32x16 zero16() {
    f32x16 z;
#pragma unroll
    for (int i = 0; i < 16; ++i) z[i] = 0.f;
    return z;
}

// convert 8 consecutive fp32 (32B, 16B-aligned) -> 8 bf16 packed in int4v
__device__ __forceinline__ int4v cvt8(const float* __restrict__ p) {
    const float4* q = (const float4*)p;
    float4 f0 = q[0], f1 = q[1];
    union { u16 u[8]; int4v v; } r;
    r.u[0]=f2b(f0.x); r.u[1]=f2b(f0.y); r.u[2]=f2b(f0.z); r.u[3]=f2b(f0.w);
    r.u[4]=f2b(f1.x); r.u[5]=f2b(f1.y); r.u[6]=f2b(f1.z); r.u[7]=f2b(f1.w);
    return r.v;
}

__device__ __forceinline__ f32x16 mfma16(bf16x8 a, bf16x8 b, f32x16 c) {
    return __builtin_amdgcn_mfma_f32_32x32x16_bf16(a, b, c, 0, 0, 0);
}

// ---------------- prep: transpose+convert weights, convert h ----------------
__global__ void prep_kernel(const float* __restrict__ h,
                            const float* __restrict__ W1m, const float* __restrict__ W2m,
                            const float* __restrict__ W1u, const float* __restrict__ W2u,
                            u16* __restrict__ w1tm, u16* __restrict__ w2tm,
                            u16* __restrict__ w1tu, u16* __restrict__ w2tu,
                            u16* __restrict__ hbuf, int do_h)
{
    int tid = blockIdx.x * blockDim.x + threadIdx.x;
    int stride = gridDim.x * blockDim.x;
    for (int i = tid; i < 128 * 256; i += stride) {
        int n = i >> 8, k = i & 255;
        w1tm[i] = f2b(W1m[k * 128 + n]);
        w1tu[i] = f2b(W1u[k * 128 + n]);
    }
    for (int i = tid; i < 128 * 128; i += stride) {
        int n = i >> 7, k = i & 127;
        w2tm[i] = f2b(W2m[k * 128 + n]);
        w2tu[i] = f2b(W2u[k * 128 + n]);
    }
    if (do_h) {
        for (int i = tid; i < NN * DD / 8; i += stride) {
            *(int4v*)(hbuf + (size_t)i * 8) = cvt8(h + (size_t)i * 8);
        }
    }
}

// ---------------- edge kernel: msg MLP + atomic scatter into agg ----------------
__global__ __launch_bounds__(512, 1) void edge_kernel(
    const float* __restrict__ h, const u16* __restrict__ hb, int use_hb,
    const int* __restrict__ edges,
    const u16* __restrict__ w1t, const u16* __restrict__ w2t,
    const float* __restrict__ bias1, const float* __restrict__ bias2,
    float* __restrict__ agg)
{
    extern __shared__ char sm[];
    char* w1l = sm + SM_W1;
    char* w2l = sm + SM_W2;
    char* pr  = sm + SM_PR;
    int* dstl = (int*)(sm + SM_DST);

    const int tid  = threadIdx.x;
    const int lane = tid & 63;
    const int wid  = tid >> 6;       // 0..7
    const int wr   = wid >> 1;       // 0..3 (row wave)
    const int wc   = wid & 1;        // 0..1 (col wave)
    const int l31  = lane & 31;
    const int kg   = lane >> 5;      // 0..1
    const int arow = wr * 32 + l31;          // tile-local edge row this lane reads for A
    const int bcol0 = wc * 64 + l31;         // output cols
    const int bcol1 = bcol0 + 32;

    // stage weights once per (persistent) block
    for (int i = tid; i < 4096; i += 512) {          // W1t: 128 n x 32 chunks
        int n = i >> 5, c = i & 31;
        int4v v = *(const int4v*)(w1t + n * 256 + c * 8);
        *(int4v*)(w1l + n * 512 + ((c ^ (n & 7)) << 4)) = v;
    }
    for (int i = tid; i < 2048; i += 512) {          // W2t: 128 n x 16 chunks
        int n = i >> 4, c = i & 15;
        int4v v = *(const int4v*)(w2t + n * 128 + c * 8);
        *(int4v*)(w2l + n * 256 + ((c ^ (n & 7)) << 4)) = v;
    }

    const float b1v0 = bias1[bcol0], b1v1 = bias1[bcol1];
    const float b2v0 = bias2[bcol0], b2v1 = bias2[bcol1];

    const int ntiles = (NE + 127) >> 7;   // 4688 (tail tile = 64 edges)
    for (int tile = blockIdx.x; tile < ntiles; tile += gridDim.x) {
        const int e0 = tile << 7;
        __syncthreads();   // protect LDS (weights staged / previous-tile readers done)

        if (tid < 128) {
            int er = e0 + tid;
            dstl[tid] = (er < NE) ? edges[er * 2 + 1] : 0;
        }

        f32x16 acc0 = zero16(), acc1 = zero16();

        // GEMM1 over K=256, staged as two 128-wide halves (src rows then dst rows)
        for (int half = 0; half < 2; ++half) {
            for (int i = tid; i < 2048; i += 512) {       // 128 rows x 16 chunks
                int row = i >> 4, c = i & 15;
                int er = e0 + row;
                int4v v;
                if (er < NE) {
                    int node = edges[er * 2 + half];
                    if (use_hb) v = *(const int4v*)(hb + (size_t)node * 128 + c * 8);
                    else        v = cvt8(h + (size_t)node * 128 + c * 8);
                } else v = zero4();
                *(int4v*)(pr + row * 256 + ((c ^ (row & 7)) << 4)) = v;
            }
            __syncthreads();

#pragma unroll
            for (int kk = 0; kk < 8; ++kk) {
                int ch = kk * 2 + kg;
                bf16x8 a = *(const bf16x8*)(pr + arow * 256 + ((ch ^ (arow & 7)) << 4));
                int chB = (half * 8 + kk) * 2 + kg;
                bf16x8 bw0 = *(const bf16x8*)(w1l + bcol0 * 512 + ((chB ^ (bcol0 & 7)) << 4));
                bf16x8 bw1 = *(const bf16x8*)(w1l + bcol1 * 512 + ((chB ^ (bcol1 & 7)) << 4));
                acc0 = mfma16(a, bw0, acc0);
                acc1 = mfma16(a, bw1, acc1);
            }
            __syncthreads();  // pair half consumed
        }

        // epilogue1: bias+relu -> bf16 hidden tile (aliases pair buffer)
#pragma unroll
        for (int r = 0; r < 16; ++r) {
            int grow = wr * 32 + (r & 3) + 8 * (r >> 2) + 4 * kg;
            float v0 = fmaxf(acc0[r] + b1v0, 0.f);
            float v1 = fmaxf(acc1[r] + b1v1, 0.f);
            *(u16*)(pr + grow * 256 + (((bcol0 >> 3) ^ (grow & 7)) << 4) + ((bcol0 & 7) * 2)) = f2b(v0);
            *(u16*)(pr + grow * 256 + (((bcol1 >> 3) ^ (grow & 7)) << 4) + ((bcol1 & 7) * 2)) = f2b(v1);
        }
        __syncthreads();  // hidden ready

        // GEMM2: hidden(128x128) @ W2
        f32x16 c0 = zero16(), c1 = zero16();
#pragma unroll
        for (int kk = 0; kk < 8; ++kk) {
            int ch = kk * 2 + kg;
            bf16x8 a = *(const bf16x8*)(pr + arow * 256 + ((ch ^ (arow & 7)) << 4));
            bf16x8 bw0 = *(const bf16x8*)(w2l + bcol0 * 256 + ((ch ^ (bcol0 & 7)) << 4));
            bf16x8 bw1 = *(const bf16x8*)(w2l + bcol1 * 256 + ((ch ^ (bcol1 & 7)) << 4));
            c0 = mfma16(a, bw0, c0);
            c1 = mfma16(a, bw1, c1);
        }

        // epilogue2: + b2, atomic scatter-add into agg[dst]
#pragma unroll
        for (int r = 0; r < 16; ++r) {
            int lrow = wr * 32 + (r & 3) + 8 * (r >> 2) + 4 * kg;
            if (e0 + lrow < NE) {
                int dn = dstl[lrow];
                atomicAdd(&agg[(size_t)dn * 128 + bcol0], c0[r] + b2v0);
                atomicAdd(&agg[(size_t)dn * 128 + bcol1], c1[r] + b2v1);
            }
        }
    }
}

// ---------------- node kernel: upd MLP + residual ----------------
__global__ __launch_bounds__(512, 1) void node_kernel(
    const float* __restrict__ h, const u16* __restrict__ hb, int use_hb,
    const float* __restrict__ aggin,
    const u16* __restrict__ w1t, const u16* __restrict__ w2t,
    const float* __restrict__ bias1, const float* __restrict__ bias2,
    float* __restrict__ outp)
{
    extern __shared__ char sm[];
    char* w1l = sm + SM_W1;
    char* w2l = sm + SM_W2;
    char* pr  = sm + SM_PR;

    const int tid  = threadIdx.x;
    const int lane = tid & 63;
    const int wid  = tid >> 6;
    const int wr   = wid >> 1;
    const int wc   = wid & 1;
    const int l31  = lane & 31;
    const int kg   = lane >> 5;
    const int arow = wr * 32 + l31;
    const int bcol0 = wc * 64 + l31;
    const int bcol1 = bcol0 + 32;

    for (int i = tid; i < 4096; i += 512) {
        int n = i >> 5, c = i & 31;
        int4v v = *(const int4v*)(w1t + n * 256 + c * 8);
        *(int4v*)(w1l + n * 512 + ((c ^ (n & 7)) << 4)) = v;
    }
    for (int i = tid; i < 2048; i += 512) {
        int n = i >> 4, c = i & 15;
        int4v v = *(const int4v*)(w2t + n * 128 + c * 8);
        *(int4v*)(w2l + n * 256 + ((c ^ (n & 7)) << 4)) = v;
    }

    const float b1v0 = bias1[bcol0], b1v1 = bias1[bcol1];
    const float b2v0 = bias2[bcol0], b2v1 = bias2[bcol1];

    const int ntiles = (NN + 127) >> 7;   // 391 (tail = 80 rows)
    for (int tile = blockIdx.x; tile < ntiles; tile += gridDim.x) {
        const int n0 = tile << 7;
        __syncthreads();

        f32x16 acc0 = zero16(), acc1 = zero16();

        for (int half = 0; half < 2; ++half) {
            for (int i = tid; i < 2048; i += 512) {
                int row = i >> 4, c = i & 15;
                int node = n0 + row;
                int4v v = zero4();
                if (node < NN) {
                    if (half == 0) {
                        if (use_hb) v = *(const int4v*)(hb + (size_t)node * 128 + c * 8);
                        else        v = cvt8(h + (size_t)node * 128 + c * 8);
                    } else {
                        v = cvt8(aggin + (size_t)node * 128 + c * 8);
                    }
                }
                *(int4v*)(pr + row * 256 + ((c ^ (row & 7)) << 4)) = v;
            }
            __syncthreads();

#pragma unroll
            for (int kk = 0; kk < 8; ++kk) {
                int ch = kk * 2 + kg;
                bf16x8 a = *(const bf16x8*)(pr + arow * 256 + ((ch ^ (arow & 7)) << 4));
                int chB = (half * 8 + kk) * 2 + kg;
                bf16x8 bw0 = *(const bf16x8*)(w1l + bcol0 * 512 + ((chB ^ (bcol0 & 7)) << 4));
                bf16x8 bw1 = *(const bf16x8*)(w1l + bcol1 * 512 + ((chB ^ (bcol1 & 7)) << 4));
                acc0 = mfma16(a, bw0, acc0);
                acc1 = mfma16(a, bw1, acc1);
            }
            __syncthreads();
        }

#pragma unroll
        for (int r = 0; r < 16; ++r) {
            int grow = wr * 32 + (r & 3) + 8 * (r >> 2) + 4 * kg;
            float v0 = fmaxf(acc0[r] + b1v0, 0.f);
            float v1 = fmaxf(acc1[r] + b1v1, 0.f);
            *(u16*)(pr + grow * 256 + (((bcol0 >> 3) ^ (grow & 7)) << 4) + ((bcol0 & 7) * 2)) = f2b(v0);
            *(u16*)(pr + grow * 256 + (((bcol1 >> 3) ^ (grow & 7)) << 4) + ((bcol1 & 7) * 2)) = f2b(v1);
        }
        __syncthreads();

        f32x16 c0 = zero16(), c1 = zero16();
#pragma unroll
        for (int kk = 0; kk < 8; ++kk) {
            int ch = kk * 2 + kg;
            bf16x8 a = *(const bf16x8*)(pr + arow * 256 + ((ch ^ (arow & 7)) << 4));
            bf16x8 bw0 = *(const bf16x8*)(w2l + bcol0 * 256 + ((ch ^ (bcol0 & 7)) << 4));
            bf16x8 bw1 = *(const bf16x8*)(w2l + bcol1 * 256 + ((ch ^ (bcol1 & 7)) << 4));
            c0 = mfma16(a, bw0, c0);
            c1 = mfma16(a, bw1, c1);
        }

        // epilogue: out = h + (c + b2); overwrites agg rows owned by this block only
#pragma unroll
        for (int r = 0; r < 16; ++r) {
            int lrow = wr * 32 + (r & 3) + 8 * (r >> 2) + 4 * kg;
            int node = n0 + lrow;
            if (node < NN) {
                size_t o0 = (size_t)node * 128 + bcol0;
                size_t o1 = (size_t)node * 128 + bcol1;
                outp[o0] = c0[r] + b2v0 + h[o0];
                outp[o1] = c1[r] + b2v1 + h[o1];
            }
        }
    }
}

extern "C" void kernel_launch(void* const* d_in, const int* in_sizes, int n_in,
                              void* d_out, int out_size, void* d_ws, size_t ws_size,
                              hipStream_t stream) {
    const float* h   = (const float*)d_in[0];
    const int* edges = (const int*)d_in[1];
    const float* W1m = (const float*)d_in[2];
    const float* b1m = (const float*)d_in[3];
    const float* W2m = (const float*)d_in[4];
    const float* b2m = (const float*)d_in[5];
    const float* W1u = (const float*)d_in[6];
    const float* b1u = (const float*)d_in[7];
    const float* W2u = (const float*)d_in[8];
    const float* b2u = (const float*)d_in[9];
    float* out = (float*)d_out;

    char* ws = (char*)d_ws;
    u16* w1tm = (u16*)(ws);
    u16* w2tm = (u16*)(ws + 65536);
    u16* w1tu = (u16*)(ws + 98304);
    u16* w2tu = (u16*)(ws + 163840);
    u16* hb   = (u16*)(ws + 196608);
    int use_hb = (ws_size >= 196608ull + (size_t)NN * DD * 2) ? 1 : 0;

    (void)hipFuncSetAttribute((const void*)edge_kernel,
                              hipFuncAttributeMaxDynamicSharedMemorySize, SMEM_TOTAL);
    (void)hipFuncSetAttribute((const void*)node_kernel,
                              hipFuncAttributeMaxDynamicSharedMemorySize, SMEM_TOTAL);

    hipMemsetAsync(d_out, 0, (size_t)NN * DD * sizeof(float), stream);
    prep_kernel<<<512, 256, 0, stream>>>(h, W1m, W2m, W1u, W2u,
                                         w1tm, w2tm, w1tu, w2tu, hb, use_hb);
    edge_kernel<<<256, 512, SMEM_TOTAL, stream>>>(h, hb, use_hb, edges,
                                                  w1tm, w2tm, b1m, b2m, out);
    node_kernel<<<391, 512, SMEM_TOTAL, stream>>>(h, hb, use_hb, out,
                                                  w1tu, w2tu, b1u, b2u, out);
}